// Round 2
// baseline (504.263 us; speedup 1.0000x reference)
//
#include <hip/hip_runtime.h>

#define FFT_N   4096
#define THREADS 256

__device__ __forceinline__ float2 cmul(float2 a, float2 b) {
    return make_float2(a.x*b.x - a.y*b.y, a.x*b.y + a.y*b.x);
}
__device__ __forceinline__ float2 cadd(float2 a, float2 b){ return make_float2(a.x+b.x, a.y+b.y); }
__device__ __forceinline__ float2 csub(float2 a, float2 b){ return make_float2(a.x-b.x, a.y-b.y); }

// multiply by S*i  (S=-1: forward, S=+1: inverse)
template<int S>
__device__ __forceinline__ float2 muli(float2 z) {
    return (S < 0) ? make_float2(z.y, -z.x) : make_float2(-z.y, z.x);
}

// 4-point DFT: y[k] = sum_n a_n exp(S*2pi*i*n*k/4)
template<int S>
__device__ __forceinline__ void dft4(float2 a0, float2 a1, float2 a2, float2 a3,
                                     float2& y0, float2& y1, float2& y2, float2& y3) {
    float2 e0 = cadd(a0, a2), e1 = cadd(a1, a3);
    float2 o0 = csub(a0, a2), o1 = muli<S>(csub(a1, a3));
    y0 = cadd(e0, e1); y2 = csub(e0, e1);
    y1 = cadd(o0, o1); y3 = csub(o0, o1);
}

// 16-point DFT in registers: a[k] <- sum_n a[n] exp(S*2pi*i*n*k/16)
template<int S>
__device__ __forceinline__ void dft16(float2* a) {
    const float C1 = 0.92387953251128674f;   // cos(pi/8)
    const float S1 = 0.38268343236508978f;   // sin(pi/8)
    const float R2 = 0.70710678118654752f;
    const float sg = (S < 0) ? -1.0f : 1.0f;
    const float2 w1 = make_float2( C1,  sg*S1);
    const float2 w2 = make_float2( R2,  sg*R2);
    const float2 w3 = make_float2( S1,  sg*C1);
    const float2 w6 = make_float2(-R2,  sg*R2);
    const float2 w9 = make_float2(-C1, -sg*S1);
    float2 t[16];
    // inner DFT4 over n1 of a[4*n1 + n2] -> t[n2*4 + k1]
    dft4<S>(a[0], a[4], a[8],  a[12], t[0],  t[1],  t[2],  t[3]);
    dft4<S>(a[1], a[5], a[9],  a[13], t[4],  t[5],  t[6],  t[7]);
    dft4<S>(a[2], a[6], a[10], a[14], t[8],  t[9],  t[10], t[11]);
    dft4<S>(a[3], a[7], a[11], a[15], t[12], t[13], t[14], t[15]);
    // twiddle: t[n2*4+k1] *= W16^{S*n2*k1}
    t[5]  = cmul(t[5],  w1);  t[6]  = cmul(t[6],  w2);  t[7]  = cmul(t[7],  w3);
    t[9]  = cmul(t[9],  w2);  t[10] = muli<S>(t[10]);   t[11] = cmul(t[11], w6);
    t[13] = cmul(t[13], w3);  t[14] = cmul(t[14], w6);  t[15] = cmul(t[15], w9);
    // outer DFT4 over n2 per k1 -> a[4*k2 + k1]
    dft4<S>(t[0], t[4], t[8],  t[12], a[0], a[4], a[8],  a[12]);
    dft4<S>(t[1], t[5], t[9],  t[13], a[1], a[5], a[9],  a[13]);
    dft4<S>(t[2], t[6], t[10], t[14], a[2], a[6], a[10], a[14]);
    dft4<S>(t[3], t[7], t[11], t[15], a[3], a[7], a[11], a[15]);
}

// R[k] *= exp(S*2pi*i*p*k/M), k=1..15.
// Tree-structured powering: dep depth ~5 cmuls (was 15 serial), low liveness.
template<int S>
__device__ __forceinline__ void twiddle_apply(float2* R, int p, float invM) {
    float ang = 6.283185307179586f * (float)p * invM;
    if (S < 0) ang = -ang;
    float s, c;
    __sincosf(ang, &s, &c);
    float2 w[16];
    w[1] = make_float2(c, s);
    w[2] = cmul(w[1], w[1]);
    w[3] = cmul(w[2], w[1]);
    w[4] = cmul(w[2], w[2]);
    #pragma unroll
    for (int k = 5; k < 16; ++k) w[k] = cmul(w[k-4], w[4]);
    #pragma unroll
    for (int k = 1; k < 16; ++k) R[k] = cmul(R[k], w[k]);
}

// XOR swizzle on float2 index: bits 1..3 ^= bits 4..6.
// - preserves bit 0  -> even/odd pairs stay adjacent & 16B aligned (b128-able)
// - stride-256 (A/E), stride-16-in-256 (B/D), contiguous-16 (C) all spread
//   exactly 4 lanes/bank-pair (b64) or 8 lanes/16B-segment (b128) = conflict-free
// - involution within each 128-float2 group -> bijective on [0,4096)
__device__ __forceinline__ int swz(int i) { return i ^ (((i >> 4) & 7) << 1); }

__global__ __launch_bounds__(THREADS, 5) void afdf_fft_kernel(
    const float* __restrict__ x,   // (B, 4096, 2)
    const float* __restrict__ A,   // (1, 4096, 2)
    const float* __restrict__ D,   // (1, 4096, 2)
    float* __restrict__ out)       // (B, 4096, 2)
{
    // 4096 float2 = 32768 B exactly -> 5 blocks/CU (160 KiB exactly)
    __shared__ __align__(16) float2 sh[FFT_N];

    const int t = threadIdx.x;
    const size_t rb = (size_t)blockIdx.x * FFT_N;
    const float2* __restrict__ xr = (const float2*)x + rb;
    const float2* __restrict__ Ac = (const float2*)A;
    const float2* __restrict__ Dc = (const float2*)D;
    float2* __restrict__ o        = (float2*)out + rb;

    float2 r[16];

    // ---- Phase A: global load + A-scale + S1 (16-pt DFT over stride-256) ----
    {
        const int p = t;
        // swz(p + 256k) = (p ^ mask_p) + 256k  (XOR bits don't reach the +256k bits)
        const int pa = p ^ (((p >> 4) & 7) << 1);
        #pragma unroll
        for (int n1 = 0; n1 < 16; ++n1) {
            float2 v = xr[p + 256*n1];
            float2 a = Ac[p + 256*n1];
            r[n1] = make_float2(a.x*v.x, a.y*v.y);
        }
        dft16<-1>(r);
        twiddle_apply<-1>(r, p, 1.0f/4096.0f);          // W4096^{p*k}
        #pragma unroll
        for (int k = 0; k < 16; ++k) sh[pa + 256*k] = r[k];
    }
    __syncthreads();

    // ---- Phase B: S2 (within 256-blocks, stride 16) ----
    {
        const int b = t >> 4, p2 = t & 15, base = b*256;
        #pragma unroll
        for (int n1 = 0; n1 < 16; ++n1) r[n1] = sh[swz(base + p2 + 16*n1)];
        dft16<-1>(r);
        twiddle_apply<-1>(r, p2, 1.0f/256.0f);          // W256^{p2*k}
        #pragma unroll
        for (int k = 0; k < 16; ++k) sh[swz(base + p2 + 16*k)] = r[k];
    }
    __syncthreads();

    // ---- Phase C: S3 + D-scale + S3^-1 in registers; b128 LDS access ----
    {
        const int cb = 16*t;
        const int u  = (t & 7) << 1;                    // thread-const swizzle mask
        #pragma unroll
        for (int m = 0; m < 8; ++m) {
            float4 v = *reinterpret_cast<const float4*>(&sh[cb + ((2*m) ^ u)]);
            r[2*m]   = make_float2(v.x, v.y);
            r[2*m+1] = make_float2(v.z, v.w);
        }
        dft16<-1>(r);
        // slot k3 holds frequency q = 256*k3 + 16*k2 + k1
        const int k1 = t >> 4, k2 = t & 15;
        #pragma unroll
        for (int k3 = 0; k3 < 16; ++k3) {
            float2 d = Dc[256*k3 + 16*k2 + k1];
            r[k3] = make_float2(d.x*r[k3].x, d.y*r[k3].y);
        }
        dft16<+1>(r);
        #pragma unroll
        for (int m = 0; m < 8; ++m) {
            float4 v = make_float4(r[2*m].x, r[2*m].y, r[2*m+1].x, r[2*m+1].y);
            *reinterpret_cast<float4*>(&sh[cb + ((2*m) ^ u)]) = v;
        }
    }
    __syncthreads();

    // ---- Phase D: S2^-1 (un-twiddle, conj DFT, stride 16) ----
    {
        const int b = t >> 4, p2 = t & 15, base = b*256;
        #pragma unroll
        for (int k = 0; k < 16; ++k) r[k] = sh[swz(base + p2 + 16*k)];
        twiddle_apply<+1>(r, p2, 1.0f/256.0f);
        dft16<+1>(r);
        #pragma unroll
        for (int n1 = 0; n1 < 16; ++n1) sh[swz(base + p2 + 16*n1)] = r[n1];
    }
    __syncthreads();

    // ---- Phase E: S1^-1 + 1/N + store ----
    {
        const int p = t;
        const int pa = p ^ (((p >> 4) & 7) << 1);
        #pragma unroll
        for (int k = 0; k < 16; ++k) r[k] = sh[pa + 256*k];
        twiddle_apply<+1>(r, p, 1.0f/4096.0f);
        dft16<+1>(r);
        const float inv = 1.0f / 4096.0f;
        #pragma unroll
        for (int n1 = 0; n1 < 16; ++n1)
            o[p + 256*n1] = make_float2(r[n1].x*inv, r[n1].y*inv);
    }
}

extern "C" void kernel_launch(void* const* d_in, const int* in_sizes, int n_in,
                              void* d_out, int out_size, void* d_ws, size_t ws_size,
                              hipStream_t stream) {
    (void)in_sizes; (void)n_in; (void)out_size; (void)d_ws; (void)ws_size;
    const float* x = (const float*)d_in[0];
    const float* A = (const float*)d_in[1];
    const float* D = (const float*)d_in[2];
    float* out = (float*)d_out;

    afdf_fft_kernel<<<dim3(8192), dim3(THREADS), 0, stream>>>(x, A, D, out);
}

// Round 4
// 471.554 us; speedup vs baseline: 1.0694x; 1.0694x over previous
//
#include <hip/hip_runtime.h>

#define FFT_N   4096
#define THREADS 256

__device__ __forceinline__ float2 cmul(float2 a, float2 b) {
    return make_float2(a.x*b.x - a.y*b.y, a.x*b.y + a.y*b.x);
}
__device__ __forceinline__ float2 cadd(float2 a, float2 b){ return make_float2(a.x+b.x, a.y+b.y); }
__device__ __forceinline__ float2 csub(float2 a, float2 b){ return make_float2(a.x-b.x, a.y-b.y); }

// multiply by S*i  (S=-1: forward, S=+1: inverse)
template<int S>
__device__ __forceinline__ float2 muli(float2 z) {
    return (S < 0) ? make_float2(z.y, -z.x) : make_float2(-z.y, z.x);
}

// 4-point DFT: y[k] = sum_n a_n exp(S*2pi*i*n*k/4)
template<int S>
__device__ __forceinline__ void dft4(float2 a0, float2 a1, float2 a2, float2 a3,
                                     float2& y0, float2& y1, float2& y2, float2& y3) {
    float2 e0 = cadd(a0, a2), e1 = cadd(a1, a3);
    float2 o0 = csub(a0, a2), o1 = muli<S>(csub(a1, a3));
    y0 = cadd(e0, e1); y2 = csub(e0, e1);
    y1 = cadd(o0, o1); y3 = csub(o0, o1);
}

// 16-point DFT in registers: a[k] <- sum_n a[n] exp(S*2pi*i*n*k/16)
template<int S>
__device__ __forceinline__ void dft16(float2* a) {
    const float C1 = 0.92387953251128674f;   // cos(pi/8)
    const float S1 = 0.38268343236508978f;   // sin(pi/8)
    const float R2 = 0.70710678118654752f;
    const float sg = (S < 0) ? -1.0f : 1.0f;
    const float2 w1 = make_float2( C1,  sg*S1);
    const float2 w2 = make_float2( R2,  sg*R2);
    const float2 w3 = make_float2( S1,  sg*C1);
    const float2 w6 = make_float2(-R2,  sg*R2);
    const float2 w9 = make_float2(-C1, -sg*S1);
    float2 t[16];
    dft4<S>(a[0], a[4], a[8],  a[12], t[0],  t[1],  t[2],  t[3]);
    dft4<S>(a[1], a[5], a[9],  a[13], t[4],  t[5],  t[6],  t[7]);
    dft4<S>(a[2], a[6], a[10], a[14], t[8],  t[9],  t[10], t[11]);
    dft4<S>(a[3], a[7], a[11], a[15], t[12], t[13], t[14], t[15]);
    t[5]  = cmul(t[5],  w1);  t[6]  = cmul(t[6],  w2);  t[7]  = cmul(t[7],  w3);
    t[9]  = cmul(t[9],  w2);  t[10] = muli<S>(t[10]);   t[11] = cmul(t[11], w6);
    t[13] = cmul(t[13], w3);  t[14] = cmul(t[14], w6);  t[15] = cmul(t[15], w9);
    dft4<S>(t[0], t[4], t[8],  t[12], a[0], a[4], a[8],  a[12]);
    dft4<S>(t[1], t[5], t[9],  t[13], a[1], a[5], a[9],  a[13]);
    dft4<S>(t[2], t[6], t[10], t[14], a[2], a[6], a[10], a[14]);
    dft4<S>(t[3], t[7], t[11], t[15], a[3], a[7], a[11], a[15]);
}

// R0[k],R1[k] *= exp(S*2pi*i*p*k/M), k=1..15. One sincos + tree powering,
// twiddle table SHARED between the two rows (computed once).
template<int S>
__device__ __forceinline__ void twiddle_apply2(float2* R0, float2* R1, int p, float invM) {
    float ang = 6.283185307179586f * (float)p * invM;
    if (S < 0) ang = -ang;
    float s, c;
    __sincosf(ang, &s, &c);
    float2 w[16];
    w[1] = make_float2(c, s);
    w[2] = cmul(w[1], w[1]);
    w[3] = cmul(w[2], w[1]);
    w[4] = cmul(w[2], w[2]);
    #pragma unroll
    for (int k = 5; k < 16; ++k) w[k] = cmul(w[k-4], w[4]);
    #pragma unroll
    for (int k = 1; k < 16; ++k) {
        R0[k] = cmul(R0[k], w[k]);
        R1[k] = cmul(R1[k], w[k]);
    }
}

// Swizzle on 16B (float4) slot index: bits 0..2 ^= bits 4..6.
// Bank-quad of slot i = i%8, so this spreads every access pattern used below
// (stride-256, stride-16-within-256, contiguous-16) to exactly 8 lanes per
// bank-quad per wave access = the b128 minimum (conflict-free).
// Involution within each 128-slot group -> bijective on [0,4096).
__device__ __forceinline__ int swz16(int i) { return i ^ ((i >> 4) & 7); }

__global__ __launch_bounds__(THREADS, 2) void afdf_fft_kernel(
    const float* __restrict__ x,   // (B, 4096, 2)
    const float* __restrict__ A,   // (1, 4096, 2)
    const float* __restrict__ D,   // (1, 4096, 2)
    float* __restrict__ out)       // (B, 4096, 2)
{
    // One float4 slot per point: (row0.re, row0.im, row1.re, row1.im).
    // 4096 * 16 B = 64 KiB -> 2 blocks/CU. All LDS traffic is b128.
    __shared__ __align__(16) float4 sh[FFT_N];

    const int t = threadIdx.x;
    const size_t rb = (size_t)blockIdx.x * 2 * FFT_N;
    const float2* __restrict__ xr0 = (const float2*)x + rb;
    const float2* __restrict__ xr1 = xr0 + FFT_N;
    const float2* __restrict__ Ac  = (const float2*)A;
    const float2* __restrict__ Dc  = (const float2*)D;
    float2* __restrict__ o0        = (float2*)out + rb;
    float2* __restrict__ o1        = o0 + FFT_N;

    float2 r0[16], r1[16];

    // ---- Phase A: global load + A-scale + S1 (stride-256), both rows ----
    {
        const int p = t;
        #pragma unroll
        for (int n = 0; n < 16; ++n) {
            float2 a  = Ac[p + 256*n];          // shared between rows
            float2 v0 = xr0[p + 256*n];
            float2 v1 = xr1[p + 256*n];
            r0[n] = make_float2(a.x*v0.x, a.y*v0.y);
            r1[n] = make_float2(a.x*v1.x, a.y*v1.y);
        }
        dft16<-1>(r0);
        dft16<-1>(r1);
        twiddle_apply2<-1>(r0, r1, p, 1.0f/4096.0f);    // W4096^{p*k}
        #pragma unroll
        for (int k = 0; k < 16; ++k)
            sh[swz16(p + 256*k)] = make_float4(r0[k].x, r0[k].y, r1[k].x, r1[k].y);
    }
    __syncthreads();

    // ---- Phase B: S2 (within 256-blocks, stride 16) ----
    {
        const int b = t >> 4, p2 = t & 15, base = b*256;
        #pragma unroll
        for (int n = 0; n < 16; ++n) {
            float4 v = sh[swz16(base + p2 + 16*n)];
            r0[n] = make_float2(v.x, v.y);
            r1[n] = make_float2(v.z, v.w);
        }
        dft16<-1>(r0);
        dft16<-1>(r1);
        twiddle_apply2<-1>(r0, r1, p2, 1.0f/256.0f);    // W256^{p2*k}
        #pragma unroll
        for (int k = 0; k < 16; ++k)
            sh[swz16(base + p2 + 16*k)] = make_float4(r0[k].x, r0[k].y, r1[k].x, r1[k].y);
    }
    __syncthreads();

    // ---- Phase C: S3 + D-scale (with 1/N folded in) + S3^-1, in registers ----
    {
        const int base = 16*t;
        #pragma unroll
        for (int n = 0; n < 16; ++n) {
            float4 v = sh[swz16(base + n)];
            r0[n] = make_float2(v.x, v.y);
            r1[n] = make_float2(v.z, v.w);
        }
        dft16<-1>(r0);
        dft16<-1>(r1);
        // slot k3 holds frequency q = 256*k3 + 16*k2 + k1
        const int k1 = t >> 4, k2 = t & 15;
        const float inv = 1.0f / 4096.0f;
        #pragma unroll
        for (int k3 = 0; k3 < 16; ++k3) {
            float2 d = Dc[256*k3 + 16*k2 + k1];         // shared between rows
            float dx = d.x * inv, dy = d.y * inv;
            r0[k3] = make_float2(dx*r0[k3].x, dy*r0[k3].y);
            r1[k3] = make_float2(dx*r1[k3].x, dy*r1[k3].y);
        }
        dft16<+1>(r0);
        dft16<+1>(r1);
        #pragma unroll
        for (int n = 0; n < 16; ++n)
            sh[swz16(base + n)] = make_float4(r0[n].x, r0[n].y, r1[n].x, r1[n].y);
    }
    __syncthreads();

    // ---- Phase D: S2^-1 (un-twiddle, conj DFT, stride 16) ----
    {
        const int b = t >> 4, p2 = t & 15, base = b*256;
        #pragma unroll
        for (int k = 0; k < 16; ++k) {
            float4 v = sh[swz16(base + p2 + 16*k)];
            r0[k] = make_float2(v.x, v.y);
            r1[k] = make_float2(v.z, v.w);
        }
        twiddle_apply2<+1>(r0, r1, p2, 1.0f/256.0f);
        dft16<+1>(r0);
        dft16<+1>(r1);
        #pragma unroll
        for (int n = 0; n < 16; ++n)
            sh[swz16(base + p2 + 16*n)] = make_float4(r0[n].x, r0[n].y, r1[n].x, r1[n].y);
    }
    __syncthreads();

    // ---- Phase E: S1^-1 + store (normalization already folded into D) ----
    {
        const int p = t;
        #pragma unroll
        for (int k = 0; k < 16; ++k) {
            float4 v = sh[swz16(p + 256*k)];
            r0[k] = make_float2(v.x, v.y);
            r1[k] = make_float2(v.z, v.w);
        }
        twiddle_apply2<+1>(r0, r1, p, 1.0f/4096.0f);
        dft16<+1>(r0);
        dft16<+1>(r1);
        #pragma unroll
        for (int n1 = 0; n1 < 16; ++n1) {
            o0[p + 256*n1] = r0[n1];
            o1[p + 256*n1] = r1[n1];
        }
    }
}

extern "C" void kernel_launch(void* const* d_in, const int* in_sizes, int n_in,
                              void* d_out, int out_size, void* d_ws, size_t ws_size,
                              hipStream_t stream) {
    (void)in_sizes; (void)n_in; (void)out_size; (void)d_ws; (void)ws_size;
    const float* x = (const float*)d_in[0];
    const float* A = (const float*)d_in[1];
    const float* D = (const float*)d_in[2];
    float* out = (float*)d_out;

    // 8192 rows, 2 rows per block
    afdf_fft_kernel<<<dim3(4096), dim3(THREADS), 0, stream>>>(x, A, D, out);
}

// Round 5
// 470.369 us; speedup vs baseline: 1.0721x; 1.0025x over previous
//
#include <hip/hip_runtime.h>

#define FFT_N   4096
#define THREADS 256

__device__ __forceinline__ float2 cmul(float2 a, float2 b) {
    return make_float2(a.x*b.x - a.y*b.y, a.x*b.y + a.y*b.x);
}
__device__ __forceinline__ float2 cadd(float2 a, float2 b){ return make_float2(a.x+b.x, a.y+b.y); }
__device__ __forceinline__ float2 csub(float2 a, float2 b){ return make_float2(a.x-b.x, a.y-b.y); }

// multiply by S*i  (S=-1: forward, S=+1: inverse)
template<int S>
__device__ __forceinline__ float2 muli(float2 z) {
    return (S < 0) ? make_float2(z.y, -z.x) : make_float2(-z.y, z.x);
}

// 4-point DFT: y[k] = sum_n a_n exp(S*2pi*i*n*k/4)
template<int S>
__device__ __forceinline__ void dft4(float2 a0, float2 a1, float2 a2, float2 a3,
                                     float2& y0, float2& y1, float2& y2, float2& y3) {
    float2 e0 = cadd(a0, a2), e1 = cadd(a1, a3);
    float2 o0 = csub(a0, a2), o1 = muli<S>(csub(a1, a3));
    y0 = cadd(e0, e1); y2 = csub(e0, e1);
    y1 = cadd(o0, o1); y3 = csub(o0, o1);
}

// 16-point DFT in registers: a[k] <- sum_n a[n] exp(S*2pi*i*n*k/16)
template<int S>
__device__ __forceinline__ void dft16(float2* a) {
    const float C1 = 0.92387953251128674f;   // cos(pi/8)
    const float S1 = 0.38268343236508978f;   // sin(pi/8)
    const float R2 = 0.70710678118654752f;
    const float sg = (S < 0) ? -1.0f : 1.0f;
    const float2 w1 = make_float2( C1,  sg*S1);
    const float2 w2 = make_float2( R2,  sg*R2);
    const float2 w3 = make_float2( S1,  sg*C1);
    const float2 w6 = make_float2(-R2,  sg*R2);
    const float2 w9 = make_float2(-C1, -sg*S1);
    float2 t[16];
    dft4<S>(a[0], a[4], a[8],  a[12], t[0],  t[1],  t[2],  t[3]);
    dft4<S>(a[1], a[5], a[9],  a[13], t[4],  t[5],  t[6],  t[7]);
    dft4<S>(a[2], a[6], a[10], a[14], t[8],  t[9],  t[10], t[11]);
    dft4<S>(a[3], a[7], a[11], a[15], t[12], t[13], t[14], t[15]);
    t[5]  = cmul(t[5],  w1);  t[6]  = cmul(t[6],  w2);  t[7]  = cmul(t[7],  w3);
    t[9]  = cmul(t[9],  w2);  t[10] = muli<S>(t[10]);   t[11] = cmul(t[11], w6);
    t[13] = cmul(t[13], w3);  t[14] = cmul(t[14], w6);  t[15] = cmul(t[15], w9);
    dft4<S>(t[0], t[4], t[8],  t[12], a[0], a[4], a[8],  a[12]);
    dft4<S>(t[1], t[5], t[9],  t[13], a[1], a[5], a[9],  a[13]);
    dft4<S>(t[2], t[6], t[10], t[14], a[2], a[6], a[10], a[14]);
    dft4<S>(t[3], t[7], t[11], t[15], a[3], a[7], a[11], a[15]);
}

// R0[k],R1[k] *= exp(S*2pi*i*p*k/M), k=1..15. One sincos + tree powering,
// twiddle table SHARED between the two rows (computed once).
template<int S>
__device__ __forceinline__ void twiddle_apply2(float2* R0, float2* R1, int p, float invM) {
    float ang = 6.283185307179586f * (float)p * invM;
    if (S < 0) ang = -ang;
    float s, c;
    __sincosf(ang, &s, &c);
    float2 w[16];
    w[1] = make_float2(c, s);
    w[2] = cmul(w[1], w[1]);
    w[3] = cmul(w[2], w[1]);
    w[4] = cmul(w[2], w[2]);
    #pragma unroll
    for (int k = 5; k < 16; ++k) w[k] = cmul(w[k-4], w[4]);
    #pragma unroll
    for (int k = 1; k < 16; ++k) {
        R0[k] = cmul(R0[k], w[k]);
        R1[k] = cmul(R1[k], w[k]);
    }
}

// Swizzle on 16B (float4) slot index: bits 0..2 ^= bits 4..6.
// Touches only bits 0..2 -> 16-slot-group membership (bits 4..11) preserved,
// so wave-local exchange phases stay wave-local after swizzling.
__device__ __forceinline__ int swz16(int i) { return i ^ ((i >> 4) & 7); }

// Wave-local LDS fence: all this wave's LDS writes are committed before any
// subsequent read issues. Valid replacement for __syncthreads() when the
// data exchange is entirely within one wave (here: within 16-thread groups).
// "memory" clobber stops the compiler moving ds ops across it (consumers are
// memory ops, so rule-18's sched_barrier isn't needed).
__device__ __forceinline__ void wave_lds_fence() {
    asm volatile("s_waitcnt lgkmcnt(0)" ::: "memory");
}

__global__ __launch_bounds__(THREADS, 2) void afdf_fft_kernel(
    const float* __restrict__ x,   // (B, 4096, 2)
    const float* __restrict__ A,   // (1, 4096, 2)
    const float* __restrict__ D,   // (1, 4096, 2)
    float* __restrict__ out)       // (B, 4096, 2)
{
    // One float4 slot per point: (row0.re, row0.im, row1.re, row1.im).
    // 4096 * 16 B = 64 KiB -> 2 blocks/CU. All LDS traffic is b128.
    __shared__ __align__(16) float4 sh[FFT_N];

    const int t = threadIdx.x;
    const size_t rb = (size_t)blockIdx.x * 2 * FFT_N;
    const float2* __restrict__ xr0 = (const float2*)x + rb;
    const float2* __restrict__ xr1 = xr0 + FFT_N;
    const float2* __restrict__ Ac  = (const float2*)A;
    const float2* __restrict__ Dc  = (const float2*)D;
    float2* __restrict__ o0        = (float2*)out + rb;
    float2* __restrict__ o1        = o0 + FFT_N;

    float2 r0[16], r1[16];

    // ---- Phase A: global load + A-scale + S1 (stride-256), both rows ----
    {
        const int p = t;
        #pragma unroll
        for (int n = 0; n < 16; ++n) {
            float2 a  = Ac[p + 256*n];          // shared between rows
            float2 v0 = xr0[p + 256*n];
            float2 v1 = xr1[p + 256*n];
            r0[n] = make_float2(a.x*v0.x, a.y*v0.y);
            r1[n] = make_float2(a.x*v1.x, a.y*v1.y);
        }
        dft16<-1>(r0);
        dft16<-1>(r1);
        twiddle_apply2<-1>(r0, r1, p, 1.0f/4096.0f);    // W4096^{p*k}
        #pragma unroll
        for (int k = 0; k < 16; ++k)
            sh[swz16(p + 256*k)] = make_float4(r0[k].x, r0[k].y, r1[k].x, r1[k].y);
    }
    __syncthreads();   // A->B exchange is block-wide: keep real barrier

    // ---- Phase B: S2 (within 256-blocks, stride 16) ----
    float2 dreg[16];   // D prefetch: issued here, consumed in phase C (~1 phase of latency cover)
    {
        const int k1 = t >> 4, k2 = t & 15;
        const float inv = 1.0f / 4096.0f;
        #pragma unroll
        for (int k3 = 0; k3 < 16; ++k3) {
            float2 d = Dc[256*k3 + 16*k2 + k1];
            dreg[k3] = make_float2(d.x*inv, d.y*inv);   // fold 1/N at load
        }
    }
    {
        const int b = t >> 4, p2 = t & 15, base = b*256;
        #pragma unroll
        for (int n = 0; n < 16; ++n) {
            float4 v = sh[swz16(base + p2 + 16*n)];
            r0[n] = make_float2(v.x, v.y);
            r1[n] = make_float2(v.z, v.w);
        }
        dft16<-1>(r0);
        dft16<-1>(r1);
        twiddle_apply2<-1>(r0, r1, p2, 1.0f/256.0f);    // W256^{p2*k}
        #pragma unroll
        for (int k = 0; k < 16; ++k)
            sh[swz16(base + p2 + 16*k)] = make_float4(r0[k].x, r0[k].y, r1[k].x, r1[k].y);
    }
    // B->C exchange: thread t reads [16t,16t+16) = written by its own 16-thread
    // group in phase B (disjoint per thread) -> wave-local, no block barrier.
    wave_lds_fence();

    // ---- Phase C: S3 + D-scale (1/N folded) + S3^-1, in registers ----
    {
        const int base = 16*t;
        #pragma unroll
        for (int n = 0; n < 16; ++n) {
            float4 v = sh[swz16(base + n)];
            r0[n] = make_float2(v.x, v.y);
            r1[n] = make_float2(v.z, v.w);
        }
        dft16<-1>(r0);
        dft16<-1>(r1);
        // slot k3 holds frequency q = 256*k3 + 16*k2 + k1
        #pragma unroll
        for (int k3 = 0; k3 < 16; ++k3) {
            r0[k3] = make_float2(dreg[k3].x*r0[k3].x, dreg[k3].y*r0[k3].y);
            r1[k3] = make_float2(dreg[k3].x*r1[k3].x, dreg[k3].y*r1[k3].y);
        }
        dft16<+1>(r0);
        dft16<+1>(r1);
        #pragma unroll
        for (int n = 0; n < 16; ++n)
            sh[swz16(base + n)] = make_float4(r0[n].x, r0[n].y, r1[n].x, r1[n].y);
    }
    // C->D exchange: same 16-thread-group locality -> wave-local.
    wave_lds_fence();

    // ---- Phase D: S2^-1 (un-twiddle, conj DFT, stride 16) ----
    {
        const int b = t >> 4, p2 = t & 15, base = b*256;
        #pragma unroll
        for (int k = 0; k < 16; ++k) {
            float4 v = sh[swz16(base + p2 + 16*k)];
            r0[k] = make_float2(v.x, v.y);
            r1[k] = make_float2(v.z, v.w);
        }
        twiddle_apply2<+1>(r0, r1, p2, 1.0f/256.0f);
        dft16<+1>(r0);
        dft16<+1>(r1);
        #pragma unroll
        for (int n = 0; n < 16; ++n)
            sh[swz16(base + p2 + 16*n)] = make_float4(r0[n].x, r0[n].y, r1[n].x, r1[n].y);
    }
    __syncthreads();   // D->E exchange is block-wide: keep real barrier

    // ---- Phase E: S1^-1 + store (normalization already folded into D) ----
    {
        const int p = t;
        #pragma unroll
        for (int k = 0; k < 16; ++k) {
            float4 v = sh[swz16(p + 256*k)];
            r0[k] = make_float2(v.x, v.y);
            r1[k] = make_float2(v.z, v.w);
        }
        twiddle_apply2<+1>(r0, r1, p, 1.0f/4096.0f);
        dft16<+1>(r0);
        dft16<+1>(r1);
        #pragma unroll
        for (int n1 = 0; n1 < 16; ++n1) {
            o0[p + 256*n1] = r0[n1];
            o1[p + 256*n1] = r1[n1];
        }
    }
}

extern "C" void kernel_launch(void* const* d_in, const int* in_sizes, int n_in,
                              void* d_out, int out_size, void* d_ws, size_t ws_size,
                              hipStream_t stream) {
    (void)in_sizes; (void)n_in; (void)out_size; (void)d_ws; (void)ws_size;
    const float* x = (const float*)d_in[0];
    const float* A = (const float*)d_in[1];
    const float* D = (const float*)d_in[2];
    float* out = (float*)d_out;

    // 8192 rows, 2 rows per block
    afdf_fft_kernel<<<dim3(4096), dim3(THREADS), 0, stream>>>(x, A, D, out);
}